// Round 2
// baseline (1045.484 us; speedup 1.0000x reference)
//
#include <hip/hip_runtime.h>
#include <math.h>

// Problem constants (from reference)
constexpr int NN = 50000;   // nodes
constexpr int NE = 800000;  // edges
constexpr int DD = 64;      // feature dim

// ---- wave reductions (64 lanes) ----
__device__ __forceinline__ float wave_max(float v) {
    #pragma unroll
    for (int off = 32; off > 0; off >>= 1) v = fmaxf(v, __shfl_xor(v, off, 64));
    return v;
}
__device__ __forceinline__ float wave_sum(float v) {
    #pragma unroll
    for (int off = 32; off > 0; off >>= 1) v += __shfl_xor(v, off, 64);
    return v;
}

// ---- kernel 1: zero degree histogram ----
__global__ void k_init(int* __restrict__ deg) {
    int i = blockIdx.x * blockDim.x + threadIdx.x;
    if (i < NN) deg[i] = 0;
}

// ---- kernel 2: receiver degree histogram ----
__global__ void k_count(const int* __restrict__ receivers, int* __restrict__ deg) {
    int e = blockIdx.x * blockDim.x + threadIdx.x;
    if (e < NE) atomicAdd(deg + receivers[e], 1);
}

// ---- kernel 3: exclusive scan of deg -> starts (single block, 1024 threads) ----
__global__ __launch_bounds__(1024) void k_scan(const int* __restrict__ deg,
                                               int* __restrict__ starts) {
    __shared__ int buf0[1024], buf1[1024];
    const int t = threadIdx.x;
    constexpr int C = (NN + 1023) / 1024;   // 49 nodes per thread
    int lo = t * C; if (lo > NN) lo = NN;
    int hi = lo + C; if (hi > NN) hi = NN;
    int s = 0;
    for (int i = lo; i < hi; ++i) s += deg[i];
    buf0[t] = s;
    __syncthreads();
    int* src = buf0; int* dst = buf1;
    for (int off = 1; off < 1024; off <<= 1) {
        int v = src[t] + ((t >= off) ? src[t - off] : 0);
        dst[t] = v;
        __syncthreads();
        int* tmp = src; src = dst; dst = tmp;
    }
    // src now holds inclusive scan of per-thread sums
    int run = (t == 0) ? 0 : src[t - 1];
    for (int i = lo; i < hi; ++i) { starts[i] = run; run += deg[i]; }
}

// ---- kernel 4: fill CSR edge index (starts advanced to segment ends) ----
__global__ void k_fill(const int* __restrict__ receivers,
                       int* __restrict__ starts, int* __restrict__ eidx) {
    int e = blockIdx.x * blockDim.x + threadIdx.x;
    if (e < NE) {
        int pos = atomicAdd(starts + receivers[e], 1);
        eidx[pos] = e;
    }
}

// ---- kernel 5: node projections, transposed (lane owns a node row) ----
// wave w handles matrix m = w/782, nodes [(w%782)*64 + lane]. acc[64] in VGPRs;
// W[k][j] is a wave-uniform load -> s_load (free SGPR operand in the FMA).
__global__ __launch_bounds__(256) void k_node(
    const float* __restrict__ nodes,
    const float* __restrict__ Wsent, const float* __restrict__ bsent,
    const float* __restrict__ Wrecv, const float* __restrict__ brecv,
    const float* __restrict__ Wmsg,  const float* __restrict__ bmsg,
    const float* __restrict__ Wself, const float* __restrict__ bself,
    float* __restrict__ sentP, float* __restrict__ recvP,
    float* __restrict__ msgP,  float* __restrict__ selfOut) {
    const int lane = threadIdx.x & 63;
    const int w = (blockIdx.x * 256 + threadIdx.x) >> 6;   // 0..3127
    const int m = w / 782;
    const int i = (w % 782) * 64 + lane;
    if (i >= NN) return;

    const float* W; const float* bias; float* out;
    if (m == 0)      { W = Wsent; bias = bsent; out = sentP; }
    else if (m == 1) { W = Wrecv; bias = brecv; out = recvP; }
    else if (m == 2) { W = Wmsg;  bias = bmsg;  out = msgP; }
    else             { W = Wself; bias = bself; out = selfOut; }

    float acc[DD];
    #pragma unroll
    for (int j = 0; j < DD; ++j) acc[j] = bias[j];   // uniform load

    const float* xrow = nodes + (size_t)i * DD;
    for (int kc = 0; kc < 4; ++kc) {                 // rolled: code size
        float4 x0 = *(const float4*)(xrow + kc * 16 + 0);
        float4 x1 = *(const float4*)(xrow + kc * 16 + 4);
        float4 x2 = *(const float4*)(xrow + kc * 16 + 8);
        float4 x3 = *(const float4*)(xrow + kc * 16 + 12);
        float xs[16] = {x0.x, x0.y, x0.z, x0.w, x1.x, x1.y, x1.z, x1.w,
                        x2.x, x2.y, x2.z, x2.w, x3.x, x3.y, x3.z, x3.w};
        #pragma unroll
        for (int kk = 0; kk < 16; ++kk) {
            const float* Wr = W + (kc * 16 + kk) * DD;  // wave-uniform row
            #pragma unroll
            for (int j = 0; j < DD; ++j) acc[j] += xs[kk] * Wr[j];
        }
    }
    float* orow = out + (size_t)i * DD;
    #pragma unroll
    for (int j4 = 0; j4 < DD / 4; ++j4) {
        float4 v; v.x = acc[j4*4+0]; v.y = acc[j4*4+1];
                  v.z = acc[j4*4+2]; v.w = acc[j4*4+3];
        *(float4*)(orow + j4 * 4) = v;
    }
}

// ---- kernel 6: edge features + attention logits, transposed ----
// lane owns edge e = w*64+lane entirely; attention dot is lane-local (no shuffle).
__global__ __launch_bounds__(256) void k_edge(
    const float* __restrict__ edges,
    const int* __restrict__ senders, const int* __restrict__ receivers,
    const float* __restrict__ Wedge, const float* __restrict__ bedge,
    const float* __restrict__ Wattn, const float* __restrict__ battn,
    const float* __restrict__ sentP, const float* __restrict__ recvP,
    float* __restrict__ edgeOut, float* __restrict__ logits) {
    const int lane = threadIdx.x & 63;
    const int w = (blockIdx.x * 256 + threadIdx.x) >> 6;  // 0..12499
    const int e = w * 64 + lane;                          // NE = 12500*64 exactly

    float acc[DD];
    #pragma unroll
    for (int j = 0; j < DD; ++j) acc[j] = bedge[j];       // uniform load

    const float* xrow = edges + (size_t)e * DD;
    for (int kc = 0; kc < 4; ++kc) {
        float4 x0 = *(const float4*)(xrow + kc * 16 + 0);
        float4 x1 = *(const float4*)(xrow + kc * 16 + 4);
        float4 x2 = *(const float4*)(xrow + kc * 16 + 8);
        float4 x3 = *(const float4*)(xrow + kc * 16 + 12);
        float xs[16] = {x0.x, x0.y, x0.z, x0.w, x1.x, x1.y, x1.z, x1.w,
                        x2.x, x2.y, x2.z, x2.w, x3.x, x3.y, x3.z, x3.w};
        #pragma unroll
        for (int kk = 0; kk < 16; ++kk) {
            const float* Wr = Wedge + (kc * 16 + kk) * DD;  // wave-uniform row
            #pragma unroll
            for (int j = 0; j < DD; ++j) acc[j] += xs[kk] * Wr[j];
        }
    }

    const int s = senders[e];
    const int r = receivers[e];
    const float* srow = sentP + (size_t)s * DD;
    const float* rrow = recvP + (size_t)r * DD;
    float* orow = edgeOut + (size_t)e * DD;
    float t = 0.0f;
    #pragma unroll
    for (int j4 = 0; j4 < DD / 4; ++j4) {
        float4 sv = *(const float4*)(srow + j4 * 4);
        float4 rv = *(const float4*)(rrow + j4 * 4);
        float4 ev;
        ev.x = acc[j4*4+0] + sv.x + rv.x;
        ev.y = acc[j4*4+1] + sv.y + rv.y;
        ev.z = acc[j4*4+2] + sv.z + rv.z;
        ev.w = acc[j4*4+3] + sv.w + rv.w;
        t += ev.x * Wattn[j4*4+0] + ev.y * Wattn[j4*4+1]
           + ev.z * Wattn[j4*4+2] + ev.w * Wattn[j4*4+3];
        *(float4*)(orow + j4 * 4) = ev;
    }
    float v = t + battn[0];
    v = v > 0.0f ? v : 0.01f * v;     // leaky_relu
    logits[e] = v;                    // coalesced store
}

// ---- kernel 7: per-node softmax + weighted message gather (no atomics) ----
// wave per node; startsAfter[n] = segment end (starts advanced by k_fill).
__global__ __launch_bounds__(256) void k_final(
    const int* __restrict__ startsAfter, const int* __restrict__ eidx,
    const int* __restrict__ senders, const float* __restrict__ logits,
    const float* __restrict__ msgP, float* __restrict__ outNodes) {
    const int lane = threadIdx.x & 63;
    const int n = (blockIdx.x * 256 + threadIdx.x) >> 6;
    if (n >= NN) return;
    const int end = startsAfter[n];
    const int beg = (n > 0) ? startsAfter[n - 1] : 0;

    float mloc = -1e30f;
    for (int b = beg + lane; b < end; b += 64)
        mloc = fmaxf(mloc, logits[eidx[b]]);
    const float m = wave_max(mloc);

    float sloc = 0.0f;
    for (int b = beg + lane; b < end; b += 64)
        sloc += expf(logits[eidx[b]] - m);
    const float denom = wave_sum(sloc);
    const float inv = 1.0f / denom;   // deg==0: loop below empty, inv unused

    float acc = 0.0f;
    for (int b = beg; b < end; ++b) {      // wave-uniform serial loop
        const int e = eidx[b];
        const float wgt = expf(logits[e] - m) * inv;
        const int s = senders[e];
        acc += wgt * msgP[(size_t)s * DD + lane];   // coalesced row gather
    }
    outNodes[(size_t)n * DD + lane] += acc;         // on top of selfOut
}

extern "C" void kernel_launch(void* const* d_in, const int* in_sizes, int n_in,
                              void* d_out, int out_size, void* d_ws, size_t ws_size,
                              hipStream_t stream) {
    const float* nodes     = (const float*)d_in[0];
    const float* edges     = (const float*)d_in[1];
    const int*   senders   = (const int*)d_in[2];
    const int*   receivers = (const int*)d_in[3];
    const float* Wsent = (const float*)d_in[4];
    const float* bsent = (const float*)d_in[5];
    const float* Wrecv = (const float*)d_in[6];
    const float* brecv = (const float*)d_in[7];
    const float* Wedge = (const float*)d_in[8];
    const float* bedge = (const float*)d_in[9];
    const float* Wattn = (const float*)d_in[10];
    const float* battn = (const float*)d_in[11];
    const float* Wmsg  = (const float*)d_in[12];
    const float* bmsg  = (const float*)d_in[13];
    const float* Wself = (const float*)d_in[14];
    const float* bself = (const float*)d_in[15];

    float* out = (float*)d_out;
    float* outNodes = out;                    // [NN, DD]
    float* outEdge  = out + (size_t)NN * DD;  // [NE, DD]

    // workspace layout (same total as previous round)
    float* ws = (float*)d_ws;
    float* sentP  = ws;                       // NN*DD floats
    float* recvP  = sentP + (size_t)NN * DD;  // NN*DD
    float* msgP   = recvP + (size_t)NN * DD;  // NN*DD
    float* logits = msgP  + (size_t)NN * DD;  // NE
    int*   deg    = (int*)(logits + NE);      // NN ints
    int*   starts = deg + NN;                 // NN ints
    int*   eidx   = starts + NN;              // NE ints

    k_init <<<(NN + 255) / 256, 256, 0, stream>>>(deg);
    k_count<<<(NE + 255) / 256, 256, 0, stream>>>(receivers, deg);
    k_scan <<<1, 1024, 0, stream>>>(deg, starts);
    k_fill <<<(NE + 255) / 256, 256, 0, stream>>>(receivers, starts, eidx);
    k_node <<<782, 256, 0, stream>>>(nodes, Wsent, bsent, Wrecv, brecv,
                                     Wmsg, bmsg, Wself, bself,
                                     sentP, recvP, msgP, outNodes);
    k_edge <<<3125, 256, 0, stream>>>(edges, senders, receivers, Wedge, bedge,
                                      Wattn, battn, sentP, recvP,
                                      outEdge, logits);
    k_final<<<(NN * 64 + 255) / 256, 256, 0, stream>>>(starts, eidx, senders,
                                                       logits, msgP, outNodes);
}

// Round 3
// 1004.525 us; speedup vs baseline: 1.0408x; 1.0408x over previous
//
#include <hip/hip_runtime.h>
#include <math.h>

// Problem constants (from reference)
constexpr int NN = 50000;   // nodes
constexpr int NE = 800000;  // edges
constexpr int DD = 64;      // feature dim

// ---- monotone float<->uint map for atomicMax on signed floats ----
__device__ __forceinline__ unsigned fmap(float x) {
    unsigned u = __float_as_uint(x);
    return (u & 0x80000000u) ? ~u : (u | 0x80000000u);
}
__device__ __forceinline__ float funmap(unsigned u) {
    unsigned b = (u & 0x80000000u) ? (u & 0x7FFFFFFFu) : ~u;
    return __uint_as_float(b);
}

// ---- kernel 1: init segment max/sum ----
__global__ void k_init(unsigned* __restrict__ segMax, float* __restrict__ segSum) {
    int i = blockIdx.x * blockDim.x + threadIdx.x;
    if (i < NN) { segMax[i] = 0u; segSum[i] = 0.0f; }
}

// ---- kernel 2: node projections ----
// Wave handles (matrix m = wid&3, node stream). Lane owns output column `lane`:
// Wc[64] pinned in VGPRs; x-row force-scalarized (readfirstlane) -> s_load into
// SGPRs; inner loop = 1 v_fmac(vgpr, sgpr) per MAC. No LDS, no spills.
__global__ __launch_bounds__(256) void k_node(
    const float* __restrict__ nodes,
    const float* __restrict__ Wsent, const float* __restrict__ bsent,
    const float* __restrict__ Wrecv, const float* __restrict__ brecv,
    const float* __restrict__ Wmsg,  const float* __restrict__ bmsg,
    const float* __restrict__ Wself, const float* __restrict__ bself,
    float* __restrict__ sentP, float* __restrict__ recvP,
    float* __restrict__ msgP,  float* __restrict__ selfOut) {
    const int lane = threadIdx.x & 63;
    const int wid  = (blockIdx.x * 256 + threadIdx.x) >> 6;
    const int nw   = (gridDim.x * 256) >> 6;
    const int m    = wid & 3;
    const int wsub = wid >> 2;
    const int nsub = nw >> 2;

    const float* W; const float* bias; float* out;
    if (m == 0)      { W = Wsent; bias = bsent; out = sentP; }
    else if (m == 1) { W = Wrecv; bias = brecv; out = recvP; }
    else if (m == 2) { W = Wmsg;  bias = bmsg;  out = msgP; }
    else             { W = Wself; bias = bself; out = selfOut; }

    float Wc[DD];                       // column `lane` of W
    #pragma unroll
    for (int k = 0; k < DD; ++k) Wc[k] = W[k * DD + lane];
    #pragma unroll
    for (int k = 0; k < DD; ++k) asm volatile("" : "+v"(Wc[k]));  // pin in VGPRs
    const float b = bias[lane];

    for (int i0 = wsub; i0 < NN; i0 += nsub) {
        const int i = __builtin_amdgcn_readfirstlane(i0);   // wave-uniform
        const float* xrow = nodes + (size_t)i * DD;
        float xs[DD];                    // uniform address -> SGPRs (s_load)
        #pragma unroll
        for (int k = 0; k < DD; ++k) xs[k] = xrow[k];
        float a0 = b, a1 = 0.0f, a2 = 0.0f, a3 = 0.0f;
        #pragma unroll
        for (int k = 0; k < 16; ++k) {
            a0 = fmaf(xs[k],      Wc[k],      a0);
            a1 = fmaf(xs[k + 16], Wc[k + 16], a1);
            a2 = fmaf(xs[k + 32], Wc[k + 32], a2);
            a3 = fmaf(xs[k + 48], Wc[k + 48], a3);
        }
        out[(size_t)i * DD + lane] = (a0 + a1) + (a2 + a3);
    }
}

// ---- kernel 3: edge features + attention logits + segment max ----
// Same template: pinned Wc column, scalarized edge row, 4 FMA chains.
__global__ __launch_bounds__(256) void k_edge(
    const float* __restrict__ edges,
    const int* __restrict__ senders, const int* __restrict__ receivers,
    const float* __restrict__ Wedge, const float* __restrict__ bedge,
    const float* __restrict__ Wattn, const float* __restrict__ battn,
    const float* __restrict__ sentP, const float* __restrict__ recvP,
    float* __restrict__ edgeOut, float* __restrict__ logits,
    unsigned* __restrict__ segMax) {
    const int lane = threadIdx.x & 63;
    const int wid  = (blockIdx.x * 256 + threadIdx.x) >> 6;
    const int nw   = (gridDim.x * 256) >> 6;

    float Wc[DD];                       // column `lane` of W_edge
    #pragma unroll
    for (int k = 0; k < DD; ++k) Wc[k] = Wedge[k * DD + lane];
    #pragma unroll
    for (int k = 0; k < DD; ++k) asm volatile("" : "+v"(Wc[k]));  // pin in VGPRs
    const float be = bedge[lane];
    const float wa = Wattn[lane];
    const float ba = battn[0];

    for (int e0 = wid; e0 < NE; e0 += nw) {
        const int e = __builtin_amdgcn_readfirstlane(e0);   // wave-uniform
        const int s = senders[e];        // scalar loads
        const int r = receivers[e];
        // per-lane gathers, issued early to overlap the FMA chain
        float g0 = sentP[(size_t)s * DD + lane];
        float g1 = recvP[(size_t)r * DD + lane];
        const float* xrow = edges + (size_t)e * DD;
        float xs[DD];                    // uniform -> SGPRs
        #pragma unroll
        for (int k = 0; k < DD; ++k) xs[k] = xrow[k];
        float a0 = be, a1 = 0.0f, a2 = 0.0f, a3 = 0.0f;
        #pragma unroll
        for (int k = 0; k < 16; ++k) {
            a0 = fmaf(xs[k],      Wc[k],      a0);
            a1 = fmaf(xs[k + 16], Wc[k + 16], a1);
            a2 = fmaf(xs[k + 32], Wc[k + 32], a2);
            a3 = fmaf(xs[k + 48], Wc[k + 48], a3);
        }
        float ef = (a0 + a1) + ((a2 + a3) + (g0 + g1));
        edgeOut[(size_t)e * DD + lane] = ef;
        // attention logit: dot(ef, Wattn) + b, leaky_relu(0.01)
        float t = ef * wa;
        #pragma unroll
        for (int off = 32; off > 0; off >>= 1) t += __shfl_xor(t, off, 64);
        if (lane == 0) {
            float v = t + ba;
            v = v > 0.0f ? v : 0.01f * v;
            logits[e] = v;
            atomicMax(segMax + r, fmap(v));
        }
    }
}

// ---- kernel 4: exp(logit - segmax), accumulate segment sums ----
__global__ void k_exp(const float* __restrict__ logits,
                      const int* __restrict__ receivers,
                      const unsigned* __restrict__ segMax,
                      float* __restrict__ expv, float* __restrict__ segSum) {
    int e = blockIdx.x * blockDim.x + threadIdx.x;
    if (e < NE) {
        int r = receivers[e];
        float m = funmap(segMax[r]);
        float ex = expf(logits[e] - m);
        expv[e] = ex;
        atomicAdd(segSum + r, ex);
    }
}

// ---- kernel 5: weighted message scatter into new_nodes ----
__global__ __launch_bounds__(256) void k_scatter(
    const int* __restrict__ senders, const int* __restrict__ receivers,
    const float* __restrict__ expv, const float* __restrict__ segSum,
    const float* __restrict__ msgP, float* __restrict__ outNodes) {
    const int lane = threadIdx.x & 63;
    const int wid  = (blockIdx.x * 256 + threadIdx.x) >> 6;
    const int nw   = (gridDim.x * 256) >> 6;
    for (int e0 = wid; e0 < NE; e0 += nw) {
        const int e = __builtin_amdgcn_readfirstlane(e0);
        const int s = senders[e];
        const int r = receivers[e];
        float w = expv[e] / segSum[r];   // scalar loads, uniform
        atomicAdd(outNodes + (size_t)r * DD + lane, w * msgP[(size_t)s * DD + lane]);
    }
}

extern "C" void kernel_launch(void* const* d_in, const int* in_sizes, int n_in,
                              void* d_out, int out_size, void* d_ws, size_t ws_size,
                              hipStream_t stream) {
    const float* nodes     = (const float*)d_in[0];
    const float* edges     = (const float*)d_in[1];
    const int*   senders   = (const int*)d_in[2];
    const int*   receivers = (const int*)d_in[3];
    const float* Wsent = (const float*)d_in[4];
    const float* bsent = (const float*)d_in[5];
    const float* Wrecv = (const float*)d_in[6];
    const float* brecv = (const float*)d_in[7];
    const float* Wedge = (const float*)d_in[8];
    const float* bedge = (const float*)d_in[9];
    const float* Wattn = (const float*)d_in[10];
    const float* battn = (const float*)d_in[11];
    const float* Wmsg  = (const float*)d_in[12];
    const float* bmsg  = (const float*)d_in[13];
    const float* Wself = (const float*)d_in[14];
    const float* bself = (const float*)d_in[15];

    float* out = (float*)d_out;
    float* outNodes = out;                    // [NN, DD]
    float* outEdge  = out + (size_t)NN * DD;  // [NE, DD]

    // workspace layout (identical to round-1)
    float* ws = (float*)d_ws;
    float* sentP  = ws;                       // NN*DD
    float* recvP  = sentP + (size_t)NN * DD;  // NN*DD
    float* msgP   = recvP + (size_t)NN * DD;  // NN*DD
    float* logits = msgP  + (size_t)NN * DD;  // NE
    float* expv   = logits + NE;              // NE
    float* segSum = expv + NE;                // NN
    unsigned* segMax = (unsigned*)(segSum + NN); // NN

    k_init<<<(NN + 255) / 256, 256, 0, stream>>>(segMax, segSum);
    k_node<<<1024, 256, 0, stream>>>(nodes, Wsent, bsent, Wrecv, brecv,
                                     Wmsg, bmsg, Wself, bself,
                                     sentP, recvP, msgP, outNodes);
    k_edge<<<2048, 256, 0, stream>>>(edges, senders, receivers, Wedge, bedge,
                                     Wattn, battn, sentP, recvP,
                                     outEdge, logits, segMax);
    k_exp<<<(NE + 255) / 256, 256, 0, stream>>>(logits, receivers, segMax, expv, segSum);
    k_scatter<<<4096, 256, 0, stream>>>(senders, receivers, expv, segSum, msgP, outNodes);
}

// Round 4
// 986.410 us; speedup vs baseline: 1.0599x; 1.0184x over previous
//
#include <hip/hip_runtime.h>
#include <math.h>

// Problem constants (from reference)
constexpr int NN = 50000;   // nodes
constexpr int NE = 800000;  // edges
constexpr int DD = 64;      // feature dim

// ---- wave reductions (64 lanes) ----
__device__ __forceinline__ float wave_max(float v) {
    #pragma unroll
    for (int off = 32; off > 0; off >>= 1) v = fmaxf(v, __shfl_xor(v, off, 64));
    return v;
}
__device__ __forceinline__ float wave_sum(float v) {
    #pragma unroll
    for (int off = 32; off > 0; off >>= 1) v += __shfl_xor(v, off, 64);
    return v;
}

// ---- row-per-lane 64x64 GEMM core ----
// Lane holds one input row (xrow, per-lane address) and a 64-wide accumulator.
// W row addresses are wave-uniform -> s_load into SGPRs; inner op is
// v_fmac_f32(vgpr_acc, sgpr_w, vgpr_x): exactly 1 VALU instr per MAC.
__device__ __forceinline__ void gemm_row(const float* __restrict__ xrow,
                                         const float* __restrict__ W,
                                         float acc[DD]) {
    for (int kc = 0; kc < 4; ++kc) {        // rolled: code size, uniform kc
        float4 x0 = *(const float4*)(xrow + kc * 16 + 0);
        float4 x1 = *(const float4*)(xrow + kc * 16 + 4);
        float4 x2 = *(const float4*)(xrow + kc * 16 + 8);
        float4 x3 = *(const float4*)(xrow + kc * 16 + 12);
        float xs[16] = {x0.x, x0.y, x0.z, x0.w, x1.x, x1.y, x1.z, x1.w,
                        x2.x, x2.y, x2.z, x2.w, x3.x, x3.y, x3.z, x3.w};
        #pragma unroll
        for (int kk = 0; kk < 16; ++kk) {
            const float* Wr = W + (kc * 16 + kk) * DD;   // wave-uniform row
            #pragma unroll
            for (int j = 0; j < DD; ++j) acc[j] = fmaf(xs[kk], Wr[j], acc[j]);
        }
    }
}

// ---- kernel 1: zero degree histogram ----
__global__ void k_init(int* __restrict__ deg) {
    int i = blockIdx.x * blockDim.x + threadIdx.x;
    if (i < NN) deg[i] = 0;
}

// ---- kernel 2: receiver degree histogram ----
__global__ void k_count(const int* __restrict__ receivers, int* __restrict__ deg) {
    int e = blockIdx.x * blockDim.x + threadIdx.x;
    if (e < NE) atomicAdd(deg + receivers[e], 1);
}

// ---- kernel 3: exclusive scan of deg -> starts (single block, 1024 threads) ----
__global__ __launch_bounds__(1024) void k_scan(const int* __restrict__ deg,
                                               int* __restrict__ starts) {
    __shared__ int buf0[1024], buf1[1024];
    const int t = threadIdx.x;
    constexpr int C = (NN + 1023) / 1024;   // 49 nodes per thread
    int lo = t * C; if (lo > NN) lo = NN;
    int hi = lo + C; if (hi > NN) hi = NN;
    int s = 0;
    for (int i = lo; i < hi; ++i) s += deg[i];
    buf0[t] = s;
    __syncthreads();
    int* src = buf0; int* dst = buf1;
    for (int off = 1; off < 1024; off <<= 1) {
        int v = src[t] + ((t >= off) ? src[t - off] : 0);
        dst[t] = v;
        __syncthreads();
        int* tmp = src; src = dst; dst = tmp;
    }
    int run = (t == 0) ? 0 : src[t - 1];
    for (int i = lo; i < hi; ++i) { starts[i] = run; run += deg[i]; }
}

// ---- kernel 4: fill CSR edge index (starts advanced to segment ends) ----
__global__ void k_fill(const int* __restrict__ receivers,
                       int* __restrict__ starts, int* __restrict__ eidx) {
    int e = blockIdx.x * blockDim.x + threadIdx.x;
    if (e < NE) {
        int pos = atomicAdd(starts + receivers[e], 1);
        eidx[pos] = e;
    }
}

// ---- kernel 5: node projections (row-per-lane, 4 matrices) ----
// wave w: matrix m = w&3, node tile w>>2. launch_bounds(256,2) -> 256-VGPR
// budget so acc[64] stays in registers (round-2 spill was the default cap).
__global__ __launch_bounds__(256, 2) void k_node(
    const float* __restrict__ nodes,
    const float* __restrict__ Wsent, const float* __restrict__ bsent,
    const float* __restrict__ Wrecv, const float* __restrict__ brecv,
    const float* __restrict__ Wmsg,  const float* __restrict__ bmsg,
    const float* __restrict__ Wself, const float* __restrict__ bself,
    float* __restrict__ sentP, float* __restrict__ recvP,
    float* __restrict__ msgP,  float* __restrict__ selfOut) {
    const int lane = threadIdx.x & 63;
    const int w    = (blockIdx.x * 256 + threadIdx.x) >> 6;  // 0..3127
    const int m    = w & 3;
    const int tile = w >> 2;                                 // 0..781
    const int iRaw = tile * 64 + lane;
    const int i    = iRaw < NN ? iRaw : NN - 1;              // clamp, keep uniform flow

    const float* W; const float* bias; float* out;
    if (m == 0)      { W = Wsent; bias = bsent; out = sentP; }
    else if (m == 1) { W = Wrecv; bias = brecv; out = recvP; }
    else if (m == 2) { W = Wmsg;  bias = bmsg;  out = msgP; }
    else             { W = Wself; bias = bself; out = selfOut; }

    float acc[DD];
    #pragma unroll
    for (int j = 0; j < DD; ++j) acc[j] = bias[j];   // uniform -> s_load

    gemm_row(nodes + (size_t)i * DD, W, acc);

    if (iRaw < NN) {
        float* orow = out + (size_t)i * DD;
        #pragma unroll
        for (int j4 = 0; j4 < DD / 4; ++j4) {
            float4 v; v.x = acc[j4*4+0]; v.y = acc[j4*4+1];
                      v.z = acc[j4*4+2]; v.w = acc[j4*4+3];
            *(float4*)(orow + j4 * 4) = v;
        }
    }
}

// ---- kernel 6: edge features + attention logits (row-per-lane) ----
// Lane owns edge e fully: attention dot is lane-local, logits store coalesced.
// No segMax atomics (softmax max/sum computed in k_final via CSR).
__global__ __launch_bounds__(256, 2) void k_edge(
    const float* __restrict__ edges,
    const int* __restrict__ senders, const int* __restrict__ receivers,
    const float* __restrict__ Wedge, const float* __restrict__ bedge,
    const float* __restrict__ Wattn, const float* __restrict__ battn,
    const float* __restrict__ sentP, const float* __restrict__ recvP,
    float* __restrict__ edgeOut, float* __restrict__ logits) {
    const int lane = threadIdx.x & 63;
    const int w = (blockIdx.x * 256 + threadIdx.x) >> 6;  // 0..12499
    const int e = w * 64 + lane;                          // NE = 12500*64 exactly

    float acc[DD];
    #pragma unroll
    for (int j = 0; j < DD; ++j) acc[j] = bedge[j];       // uniform -> s_load

    gemm_row(edges + (size_t)e * DD, Wedge, acc);

    const int s = senders[e];
    const int r = receivers[e];
    const float* srow = sentP + (size_t)s * DD;   // L2/L3-resident row gathers
    const float* rrow = recvP + (size_t)r * DD;
    float* orow = edgeOut + (size_t)e * DD;
    float t = 0.0f;
    #pragma unroll
    for (int j4 = 0; j4 < DD / 4; ++j4) {
        float4 sv = *(const float4*)(srow + j4 * 4);
        float4 rv = *(const float4*)(rrow + j4 * 4);
        float4 ev;
        ev.x = acc[j4*4+0] + sv.x + rv.x;
        ev.y = acc[j4*4+1] + sv.y + rv.y;
        ev.z = acc[j4*4+2] + sv.z + rv.z;
        ev.w = acc[j4*4+3] + sv.w + rv.w;
        t += ev.x * Wattn[j4*4+0] + ev.y * Wattn[j4*4+1]
           + ev.z * Wattn[j4*4+2] + ev.w * Wattn[j4*4+3];
        *(float4*)(orow + j4 * 4) = ev;
    }
    float v = t + battn[0];
    v = v > 0.0f ? v : 0.01f * v;     // leaky_relu
    logits[e] = v;                    // coalesced store
}

// ---- kernel 7: per-node softmax + weighted message gather (no atomics) ----
// wave per node; ends[n] = segment end (starts advanced by k_fill).
__global__ void k_final(
    const int* __restrict__ ends, const int* __restrict__ eidx,
    const int* __restrict__ senders, const float* __restrict__ logits,
    const float* __restrict__ msgP, float* __restrict__ outNodes) {
    const int lane = threadIdx.x & 63;
    const int n = (blockIdx.x * 256 + threadIdx.x) >> 6;
    if (n >= NN) return;
    const int end = ends[n];
    const int beg = (n > 0) ? ends[n - 1] : 0;
    if (end == beg) return;            // empty segment: outNodes keeps selfOut

    float mloc = -1e30f;
    for (int b = beg + lane; b < end; b += 64)
        mloc = fmaxf(mloc, logits[eidx[b]]);
    const float m = wave_max(mloc);

    float sloc = 0.0f;
    for (int b = beg + lane; b < end; b += 64)
        sloc += expf(logits[eidx[b]] - m);
    const float inv = 1.0f / wave_sum(sloc);

    // weighted gather: wave-uniform loop, unroll-2 for latency overlap
    float acc0 = 0.0f, acc1 = 0.0f;
    int b = beg;
    for (; b + 2 <= end; b += 2) {
        const int e0 = eidx[b], e1 = eidx[b + 1];         // uniform s_load
        const int s0 = senders[e0], s1 = senders[e1];
        const float w0 = expf(logits[e0] - m);
        const float w1 = expf(logits[e1] - m);
        acc0 += w0 * msgP[(size_t)s0 * DD + lane];        // coalesced rows
        acc1 += w1 * msgP[(size_t)s1 * DD + lane];
    }
    if (b < end) {
        const int e0 = eidx[b];
        acc0 += expf(logits[e0] - m) * msgP[(size_t)senders[e0] * DD + lane];
    }
    outNodes[(size_t)n * DD + lane] += (acc0 + acc1) * inv;   // on top of selfOut
}

extern "C" void kernel_launch(void* const* d_in, const int* in_sizes, int n_in,
                              void* d_out, int out_size, void* d_ws, size_t ws_size,
                              hipStream_t stream) {
    const float* nodes     = (const float*)d_in[0];
    const float* edges     = (const float*)d_in[1];
    const int*   senders   = (const int*)d_in[2];
    const int*   receivers = (const int*)d_in[3];
    const float* Wsent = (const float*)d_in[4];
    const float* bsent = (const float*)d_in[5];
    const float* Wrecv = (const float*)d_in[6];
    const float* brecv = (const float*)d_in[7];
    const float* Wedge = (const float*)d_in[8];
    const float* bedge = (const float*)d_in[9];
    const float* Wattn = (const float*)d_in[10];
    const float* battn = (const float*)d_in[11];
    const float* Wmsg  = (const float*)d_in[12];
    const float* bmsg  = (const float*)d_in[13];
    const float* Wself = (const float*)d_in[14];
    const float* bself = (const float*)d_in[15];

    float* out = (float*)d_out;
    float* outNodes = out;                    // [NN, DD]
    float* outEdge  = out + (size_t)NN * DD;  // [NE, DD]

    // workspace layout
    float* ws = (float*)d_ws;
    float* sentP  = ws;                       // NN*DD floats
    float* recvP  = sentP + (size_t)NN * DD;  // NN*DD
    float* msgP   = recvP + (size_t)NN * DD;  // NN*DD
    float* logits = msgP  + (size_t)NN * DD;  // NE
    int*   deg    = (int*)(logits + NE);      // NN ints
    int*   starts = deg + NN;                 // NN ints
    int*   eidx   = starts + NN;              // NE ints

    k_init <<<(NN + 255) / 256, 256, 0, stream>>>(deg);
    k_count<<<(NE + 255) / 256, 256, 0, stream>>>(receivers, deg);
    k_scan <<<1, 1024, 0, stream>>>(deg, starts);
    k_fill <<<(NE + 255) / 256, 256, 0, stream>>>(receivers, starts, eidx);
    k_node <<<782, 256, 0, stream>>>(nodes, Wsent, bsent, Wrecv, brecv,
                                     Wmsg, bmsg, Wself, bself,
                                     sentP, recvP, msgP, outNodes);
    k_edge <<<3125, 256, 0, stream>>>(edges, senders, receivers, Wedge, bedge,
                                      Wattn, battn, sentP, recvP,
                                      outEdge, logits);
    k_final<<<(NN * 64 + 255) / 256, 256, 0, stream>>>(starts, eidx, senders,
                                                       logits, msgP, outNodes);
}